// Round 6
// baseline (167.667 us; speedup 1.0000x reference)
//
#include <hip/hip_runtime.h>
#include <stdint.h>

// RGCNConv: out = sum_r ((A * [edge==r]) @ x) @ W_r + bias
// N=4096, IN=OUT=256, R=8.
//   k_init : out[i][o] = bias[o]
//   k_y    : y_t[o][j*8+r] = (x @ W_r)[j][o]  (bf16, in ws, 16 MB)
//   k_main : expanded GEMM out[i][o] += sum_j A[i][j]*y_t[o][j*8+e[i][j]]
//            Block 256x256 (o full-width: A/et fetched once), 8 waves,
//            wave tile 128x64 (m4 x n2) to cut LDS-read/MFMA ratio.
//            One-hot A granules built in regs (coalesced loads) -> LDS
//            (XOR-swizzled, conflict-free); B via global_load_lds 2-deep,
//            counted vmcnt(2) + one s_barrier per step.

#define NN 4096

typedef __attribute__((ext_vector_type(8)))  short s16x8;   // 8 bf16 MFMA frag
typedef __attribute__((ext_vector_type(16))) float f32x16;  // 32x32 C/D
typedef __attribute__((ext_vector_type(4)))  float fx4;
typedef __attribute__((ext_vector_type(4)))  int   ix4;
typedef __attribute__((ext_vector_type(4)))  unsigned int ux4;

union uq { ux4 u; s16x8 s; };

__device__ __forceinline__ unsigned short f2bf(float f) {
  union { float f; unsigned int u; } v; v.f = f;
  unsigned int r = v.u + 0x7fffu + ((v.u >> 16) & 1u);  // RNE
  return (unsigned short)(r >> 16);
}

__device__ __forceinline__ void gld16(const void* g, void* l) {
  __builtin_amdgcn_global_load_lds(
      (const __attribute__((address_space(1))) unsigned int*)(uintptr_t)g,
      (__attribute__((address_space(3))) unsigned int*)(uintptr_t)l, 16, 0, 0);
}

// ---------------- init: out = bias ----------------
__global__ void k_init(const float* __restrict__ bias, float* __restrict__ out) {
  int idx = blockIdx.x * 256 + threadIdx.x;
  out[idx] = bias[idx & 255];
}

// ---------------- y_t[o][j*8+r] = sum_k x[j][k] * W[r][k][o] ----------------
__global__ __launch_bounds__(256, 2) void k_y(const float* __restrict__ x,
                                              const float* __restrict__ W,
                                              unsigned short* __restrict__ yt) {
  __shared__ unsigned short Wl[128 * 256];  // 64 KB
  const int t  = threadIdx.x;
  const int j0 = blockIdx.x * 128;
  const int o0 = blockIdx.y * 16;

  {
    const int r = t >> 5, kc = t & 31;
#pragma unroll
    for (int u = 0; u < 8; ++u) {
      const int k = kc * 8 + u;
      const fx4* wp = (const fx4*)(W + ((size_t)r * 256 + k) * 256 + o0);
      fx4 w[4] = { wp[0], wp[1], wp[2], wp[3] };
#pragma unroll
      for (int i = 0; i < 16; ++i) {
        const int row = i * 8 + r;               // n'
        const int gs  = (k >> 3) ^ (row & 7);    // swizzled 16B granule
        Wl[row * 256 + gs * 8 + (k & 7)] = f2bf(w[i >> 2][i & 3]);
      }
    }
  }
  __syncthreads();

  const int lane = t & 63, wid = t >> 6;
  const int l15 = lane & 15, lh = lane >> 4;
  const int npb = wid * 32;

  fx4 acc[8][2];
#pragma unroll
  for (int m = 0; m < 8; ++m)
#pragma unroll
    for (int n = 0; n < 2; ++n) acc[m][n] = 0.f;

  unsigned int qb[2];
#pragma unroll
  for (int n = 0; n < 2; ++n) {
    int row = npb + n * 16 + l15;
    qb[n] = (unsigned)(row * 512 + 16 * (lh ^ (row & 3))) ^ (64u * ((row >> 2) & 1));
  }
  const char* WlB = (const char*)Wl;
  const float* xb = x + (size_t)(j0 + l15) * 256 + lh * 8;

#pragma unroll
  for (int ks = 0; ks < 8; ++ks) {
    s16x8 a[8];
#pragma unroll
    for (int m = 0; m < 8; ++m) {
      const fx4* xp = (const fx4*)(xb + (size_t)m * 16 * 256 + ks * 32);
      fx4 x0 = xp[0], x1 = xp[1];
      s16x8 av;
#pragma unroll
      for (int i = 0; i < 4; ++i) av[i] = (short)f2bf(x0[i]);
#pragma unroll
      for (int i = 0; i < 4; ++i) av[4 + i] = (short)f2bf(x1[i]);
      a[m] = av;
    }
#pragma unroll
    for (int n = 0; n < 2; ++n) {
      s16x8 b = *(const s16x8*)(WlB + (qb[n] ^ (unsigned)(ks * 64)));
#pragma unroll
      for (int m = 0; m < 8; ++m)
        acc[m][n] = __builtin_amdgcn_mfma_f32_16x16x32_bf16(a[m], b, acc[m][n], 0, 0, 0);
    }
  }

#pragma unroll
  for (int m = 0; m < 8; ++m)
#pragma unroll
    for (int n = 0; n < 2; ++n)
#pragma unroll
      for (int q = 0; q < 4; ++q) {
        int jl = m * 16 + lh * 4 + q;
        int np = npb + n * 16 + l15;
        int o  = o0 + (np >> 3);
        yt[(size_t)o * 32768 + (size_t)(j0 + jl) * 8 + (np & 7)] = f2bf(acc[m][n][q]);
      }
}

// ---------------- main expanded GEMM ----------------
// grid (16 itiles, 16 ksplit) = 256 blocks (1/CU). Block 256i x 256o,
// 512 thr / 8 waves, wave-grid 2(i) x 4(o), wave tile 128x64: m4 x n2
// 32x32x16 reps, acc 128 VGPR. Step = 8 j (K_eff 64, 4 MFMA k-slices).
// LDS 128 KB: A one-hot [2 buf][256 i][8 g]x16B @0, B yt [2][256 o][8 g] @64K.
// Granule slot swizzle: phys = g ^ (row&7)  (conflict-free per 8-lane phase).
// Per iter s: waitcnt vmcnt(2) lgkmcnt(0); s_barrier; DMA B(s+1);
// load A/E(s+2) coalesced b128; build+write one-hot A(s+1); compute s.
__global__ __launch_bounds__(512, 2) void k_main(const float* __restrict__ A,
                                                 const int*   __restrict__ et,
                                                 const unsigned short* __restrict__ yt,
                                                 float* __restrict__ out) {
  __shared__ ux4 smem[8192];  // 131072 B
  char* smc = (char*)smem;
  const int t = threadIdx.x, lane = t & 63, w = t >> 6;
  const int l31 = lane & 31, lh1 = lane >> 5;
  const int wm = w >> 2, wn = w & 3;
  const int i0 = blockIdx.x * 256;
  const int jb = blockIdx.y * 256;

  // builder: thread -> (row bi, j-quad bq); coalesced b128 A/E loads
  const int bi = t >> 1, bq = t & 1;
  const fx4* pA = (const fx4*)(A  + (size_t)(i0 + bi) * NN + jb + bq * 4);
  const ix4* pE = (const ix4*)(et + (size_t)(i0 + bi) * NN + jb + bq * 4);
  unsigned awr[4];
#pragma unroll
  for (int k = 0; k < 4; ++k)
    awr[k] = (unsigned)(bi * 128 + (((bq * 4 + k) ^ (bi & 7)) << 4));

  // B DMA sources (linear LDS dest, inverse-swizzled global granule)
  const ux4* ytg = (const ux4*)yt;  // [o][4096] granules
  const ux4* sB[4];
#pragma unroll
  for (int u = 0; u < 4; ++u) {
    int o  = w * 32 + u * 8 + (lane >> 3);
    int sp = lane & 7;
    sB[u] = ytg + ((size_t)o << 12) + jb + (sp ^ (o & 7));
  }

  // frag read offsets; granule g = (ks<<1)|lh1 = (ks<<1)^lh1 -> XOR-walkable
  unsigned QA[4], QB[2];
#pragma unroll
  for (int m = 0; m < 4; ++m) {
    int ir = wm * 128 + m * 32 + l31;
    QA[m] = (unsigned)(ir * 128 + ((lh1 ^ (ir & 7)) << 4));
  }
#pragma unroll
  for (int n = 0; n < 2; ++n) {
    int orow = wn * 64 + n * 32 + l31;
    QB[n] = (unsigned)(65536 + orow * 128 + ((lh1 ^ (orow & 7)) << 4));
  }

  f32x16 acc[4][2];
#pragma unroll
  for (int m = 0; m < 4; ++m)
#pragma unroll
    for (int n = 0; n < 2; ++n) acc[m][n] = 0.f;

  // prologue: AE(0), B(0) DMA, AE(1), build A(0) into buf0
  fx4 a0 = pA[0]; ix4 e0 = pE[0];
#pragma unroll
  for (int u = 0; u < 4; ++u)
    gld16(sB[u], smc + 65536 + (w * 32 + u * 8) * 128);
  fx4 aN = pA[2]; ix4 eN = pE[2];
#pragma unroll
  for (int k = 0; k < 4; ++k) {
    unsigned long long sh = ((unsigned long long)f2bf(a0[k])) << ((e0[k] & 3) * 16);
    unsigned lo = (unsigned)sh, hi = (unsigned)(sh >> 32);
    bool c = e0[k] < 4;
    ux4 q; q.x = c ? lo : 0u; q.y = c ? hi : 0u; q.z = c ? 0u : lo; q.w = c ? 0u : hi;
    *(ux4*)(smc + awr[k]) = q;
  }

  for (int s = 0; s < 32; ++s) {
    // B(s) landed (AE(s+1)=2 newer); own ds ops drained before barrier
    asm volatile("s_waitcnt vmcnt(2) lgkmcnt(0)" ::: "memory");
    __builtin_amdgcn_s_barrier();
    const int s1 = (s + 1 < 32) ? s + 1 : 31;
    const int s2 = (s + 2 < 32) ? s + 2 : 31;
    // DMA B(s+1) into buf (s+1)&1 (its old content was consumed in iter s-1)
    const unsigned bB = 65536u + (unsigned)(((s + 1) & 1) * 32768);
#pragma unroll
    for (int u = 0; u < 4; ++u)
      gld16(sB[u] + (size_t)s1 * 8, smc + bB + (w * 32 + u * 8) * 128);
    // load AE(s+2) (coalesced; lands under next step's compute)
    fx4 a2 = pA[2 * s2]; ix4 e2 = pE[2 * s2];
    // build one-hot A(s+1) into buf (s+1)&1
    const unsigned bA = (unsigned)(((s + 1) & 1) * 32768);
#pragma unroll
    for (int k = 0; k < 4; ++k) {
      unsigned long long sh = ((unsigned long long)f2bf(aN[k])) << ((eN[k] & 3) * 16);
      unsigned lo = (unsigned)sh, hi = (unsigned)(sh >> 32);
      bool c = eN[k] < 4;
      ux4 q; q.x = c ? lo : 0u; q.y = c ? hi : 0u; q.z = c ? 0u : lo; q.w = c ? 0u : hi;
      *(ux4*)(smc + bA + awr[k]) = q;
    }
    // compute step s from buf s&1
    const unsigned cO = (unsigned)((s & 1) * 32768);
#pragma unroll
    for (int ks = 0; ks < 4; ++ks) {
      uq a[4], b[2];
#pragma unroll
      for (int m = 0; m < 4; ++m)
        a[m].u = *(const ux4*)(smc + cO + (QA[m] ^ (unsigned)(ks << 5)));
#pragma unroll
      for (int n = 0; n < 2; ++n)
        b[n].u = *(const ux4*)(smc + cO + (QB[n] ^ (unsigned)(ks << 5)));
#pragma unroll
      for (int m = 0; m < 4; ++m)
#pragma unroll
        for (int n = 0; n < 2; ++n)
          acc[m][n] = __builtin_amdgcn_mfma_f32_32x32x16_bf16(a[m].s, b[n].s, acc[m][n], 0, 0, 0);
    }
    aN = a2; eN = e2;
  }
  asm volatile("s_waitcnt vmcnt(0)" ::: "memory");  // drain DMA before exit

  // epilogue: K-split partial accumulate.
  // 32x32 C layout: col = l31, row = (q&3) + 8*(q>>2) + 4*lh1
#pragma unroll
  for (int m = 0; m < 4; ++m)
#pragma unroll
    for (int n = 0; n < 2; ++n)
#pragma unroll
      for (int q = 0; q < 16; ++q) {
        int gi = i0 + wm * 128 + m * 32 + (q & 3) + 8 * (q >> 2) + 4 * lh1;
        int go = wn * 64 + n * 32 + l31;
        atomicAdd(out + (size_t)gi * 256 + go, acc[m][n][q]);
      }
}

extern "C" void kernel_launch(void* const* d_in, const int* in_sizes, int n_in,
                              void* d_out, int out_size, void* d_ws, size_t ws_size,
                              hipStream_t stream) {
  const float* x    = (const float*)d_in[0];
  const float* A    = (const float*)d_in[1];
  const int*   et   = (const int*)d_in[2];
  const float* W    = (const float*)d_in[3];
  const float* bias = (const float*)d_in[4];
  float* out = (float*)d_out;
  unsigned short* yt = (unsigned short*)d_ws;  // 16 MB

  k_init<<<dim3(4096), dim3(256), 0, stream>>>(bias, out);
  k_y   <<<dim3(32, 16), dim3(256), 0, stream>>>(x, W, yt);
  k_main<<<dim3(16, 16), dim3(512), 0, stream>>>(A, et, yt, out);
}